// Round 6
// baseline (219.736 us; speedup 1.0000x reference)
//
#include <hip/hip_runtime.h>
#include <hip/hip_bf16.h>
#include <math.h>

typedef __bf16 bf16;
typedef __bf16 bf16x4 __attribute__((ext_vector_type(4)));
typedef __bf16 bf16x8 __attribute__((ext_vector_type(8)));
typedef float f32x4 __attribute__((ext_vector_type(4)));

#define SEQ  2048
#define EMB  1024
#define NH   16
#define HD   64
#define MTOT 4096  // B*S

__device__ __forceinline__ void gl_lds16(const void* g, void* l) {
  __builtin_amdgcn_global_load_lds(
      (const __attribute__((address_space(1))) void*)g,
      (__attribute__((address_space(3))) void*)l, 16, 0, 0);
}

__device__ __forceinline__ f32x4 mfma16(bf16x8 a, bf16x8 b, f32x4 c) {
  return __builtin_amdgcn_mfma_f32_16x16x32_bf16(a, b, c, 0, 0, 0);
}

// log2(10000)/32
#define ROPE_C 0.41524101186092026f
// log2(e)/8 — QK scale, pre-folded into q at the projection epilogue
#define QSCL  0.1803368801111244f

// f32 -> bf16: 8 uniform WN-sized slices; y 0..3 = x chunks, y 4..7 = Wq..Wo.
__global__ __launch_bounds__(256) void cvt_all_kernel(
    const float* __restrict__ x,
    const float* __restrict__ w0, const float* __restrict__ w1,
    const float* __restrict__ w2, const float* __restrict__ w3,
    bf16* __restrict__ dst) {
  const int y = blockIdx.y;
  const size_t WN = (size_t)EMB * EMB;
  const float* src = (y < 4) ? (x + (size_t)y * WN)
                   : (y == 4) ? w0 : (y == 5) ? w1 : (y == 6) ? w2 : w3;
  size_t i = ((size_t)blockIdx.x * 256 + threadIdx.x) * 8;
  float4 a = *(const float4*)(src + i);
  float4 b = *(const float4*)(src + i + 4);
  bf16x8 o;
  o[0] = (bf16)a.x; o[1] = (bf16)a.y; o[2] = (bf16)a.z; o[3] = (bf16)a.w;
  o[4] = (bf16)b.x; o[5] = (bf16)b.y; o[6] = (bf16)b.z; o[7] = (bf16)b.w;
  *(bf16x8*)(dst + (size_t)y * WN + i) = o;
}

// QKV projection (unfused z, 128x128 tile, BK=64): z = blockIdx.z selects
// {q,k,v}. BK=64 halves the barrier/vmcnt(0)-drain count vs BK=32 (the m97
// structural stall) at UNCHANGED occupancy. Swizzle (both-sides, rule 21):
// LDS slot p of row r holds chunk p^(r&7); read uses chunk (kk*4+quad)^(ml&7).
// RoPE on q,k (q pre-scaled by QSCL); q,k -> [bh][s][d], v -> [bh][d][s]
// with each 32-s block PERMUTED for flash's single-b128 PV fragment.
__global__ __launch_bounds__(256) void gemm_kernel(
    const bf16* __restrict__ X,
    const bf16* __restrict__ W0, const bf16* __restrict__ W1, const bf16* __restrict__ W2,
    const float* __restrict__ B0, const float* __restrict__ B1, const float* __restrict__ B2,
    bf16* __restrict__ Oq, bf16* __restrict__ Ok, bf16* __restrict__ Ovt)
{
  const int K = EMB;
  const int tid  = threadIdx.x;
  const int lane = tid & 63;
  const int w    = tid >> 6;       // wave 0..3
  const int wm   = w >> 1, wn = w & 1;
  // XCD swizzle within each z-slice: 32-block chunks per XCD.
  const int lin = blockIdx.x + blockIdx.y * 8;
  const int sw  = (lin & 7) * 32 + (lin >> 3);
  const int tile_n = (sw & 7) * 128;
  const int tile_m = (sw >> 3) * 128;
  const int z = blockIdx.z;
  const bf16*  Wsel = (z == 0) ? W0 : (z == 1 ? W1 : W2);
  const float* Bsel = (z == 0) ? B0 : (z == 1 ? B1 : B2);

  __shared__ __align__(16) unsigned char smem[33792];  // staging 32KB | CS 33792
  bf16* As = (bf16*)smem;            // 128 x 64 = 16 KB
  bf16* Bs = (bf16*)(smem + 16384);  // 128 x 64 = 16 KB

  f32x4 acc[4][4];
#pragma unroll
  for (int i = 0; i < 4; i++)
#pragma unroll
    for (int j = 0; j < 4; j++) acc[i][j] = f32x4{0.f, 0.f, 0.f, 0.f};

  const int quad  = lane >> 4;
  const int l15   = lane & 15;
  const int srow8 = lane >> 3;   // row within an 8-row staging issue
  const int p8    = lane & 7;    // 16B-chunk slot within the 128B row
  const int csrc  = p8 ^ srow8;  // global chunk feeding this LDS slot

  for (int k0 = 0; k0 < K; k0 += 64) {
#pragma unroll
    for (int i = 0; i < 4; i++) {
      const int ii = w * 4 + i;            // 8-row group 0..15
      const int r  = ii * 8 + srow8;       // tile-local row 0..127
      gl_lds16(X    + (size_t)(tile_m + r) * K + k0 + csrc * 8, As + ii * 512);
      gl_lds16(Wsel + (size_t)(tile_n + r) * K + k0 + csrc * 8, Bs + ii * 512);
    }
    __syncthreads();

#pragma unroll
    for (int kk = 0; kk < 2; kk++) {
      bf16x8 af[4], bfr[4];
#pragma unroll
      for (int mt = 0; mt < 4; mt++) {
        int ml = wm * 64 + mt * 16 + l15;
        af[mt] = *(const bf16x8*)(As + ml * 64 + (((kk * 4 + quad) ^ (ml & 7)) & 7) * 8);
      }
#pragma unroll
      for (int nt = 0; nt < 4; nt++) {
        int nl = wn * 64 + nt * 16 + l15;
        bfr[nt] = *(const bf16x8*)(Bs + nl * 64 + (((kk * 4 + quad) ^ (nl & 7)) & 7) * 8);
      }
#pragma unroll
      for (int mt = 0; mt < 4; mt++)
#pragma unroll
        for (int nt = 0; nt < 4; nt++)
          acc[mt][nt] = mfma16(af[mt], bfr[nt], acc[mt][nt]);
    }
    __syncthreads();
  }

  // ---- epilogue ----
  bf16* CS = (bf16*)smem;  // 128 rows x 132 stride
  const int b = tile_m >> 11;
  const int s0 = tile_m & (SEQ - 1);

  if (z < 2) {
    // bias + RoPE in registers, stage CS[m][n]
#pragma unroll
    for (int nt = 0; nt < 4; nt++) {
      const int nl = wn * 64 + nt * 16 + l15;
      const int n = tile_n + nl;
      const float bias = Bsel[n];
      const int j = n & 31;
      const float invf = exp2f(-(float)j * ROPE_C);
#pragma unroll
      for (int mt = 0; mt < 4; mt++) {
#pragma unroll
        for (int r = 0; r < 4; r++) {
          const int ml = wm * 64 + mt * 16 + quad * 4 + r;
          float a = acc[mt][nt][r] + bias;
          float p = __shfl_xor(a, 1, 64);  // partner at d^1 (incl. its bias)
          float th = (float)(s0 + ml) * invf;
          float sn, cs;
          __sincosf(th, &sn, &cs);
          float res = (n & 1) ? fmaf(p, sn, a * cs) : fmaf(-p, sn, a * cs);
          if (z == 0) res *= QSCL;  // fold QK scale+log2e into q
          CS[ml * 132 + nl] = (bf16)res;
        }
      }
    }
    __syncthreads();
    // coalesced store: 256 rows (2 heads x 128 s), 128 B each
    bf16* Odst = (z == 0) ? Oq : Ok;
#pragma unroll
    for (int g = 0; g < 8; g++) {
      int unit = g * 256 + tid;
      int chunk = unit & 7;          // 16B chunk within row
      int row = unit >> 3;           // 0..255
      int hl = row >> 7, sl = row & 127;
      bf16x8 v = *(const bf16x8*)(CS + sl * 132 + hl * 64 + chunk * 8);
      int hg = (tile_n >> 6) + hl;
      size_t o = ((size_t)(b * NH + hg) * SEQ + s0 + sl) * HD + chunk * 8;
      *(bf16x8*)(Odst + o) = v;
    }
  } else {
    // V^T: stage CS[n][perm(m)] — permute s within each 32-block so flash's
    // per-lane fragment (k = hf*16 + quad*4 + e -> pos quad*8 + hf*4 + e) is
    // contiguous 16B.
#pragma unroll
    for (int nt = 0; nt < 4; nt++) {
      const int nl = wn * 64 + nt * 16 + l15;
      const float bias = Bsel[tile_n + nl];
#pragma unroll
      for (int mt = 0; mt < 4; mt++) {
        const int mb = wm * 64 + mt * 16 + quad * 4;
#pragma unroll
        for (int r = 0; r < 4; r++) {
          const int ml = mb + r;
          const int mp = (ml & ~31) | ((ml & 12) << 1) | ((ml & 16) >> 2) | (ml & 3);
          CS[nl * 132 + mp] = (bf16)(acc[mt][nt][r] + bias);
        }
      }
    }
    __syncthreads();
    // coalesced store: 128 rows (d), 256 B each
#pragma unroll
    for (int g = 0; g < 8; g++) {
      int unit = g * 256 + tid;
      int chunk = unit & 15;         // 16B chunk within row
      int row = unit >> 4;           // 0..127 (n_local)
      bf16x8 v = *(const bf16x8*)(CS + row * 132 + chunk * 8);
      int nglob = tile_n + row;
      int d = nglob & 63, hg = nglob >> 6;
      size_t o = ((size_t)(b * NH + hg) * HD + d) * SEQ + s0 + chunk * 8;
      *(bf16x8*)(Ovt + o) = v;
    }
  }
}

// Out projection: 64x128 tiles, BK=64, 512 blocks. XCD-swizzled.
__global__ __launch_bounds__(256) void gemm_o_kernel(
    const bf16* __restrict__ X,     // attn out [4096][1024] bf16
    const bf16* __restrict__ W,     // Wo [1024][1024] bf16
    const float* __restrict__ Bb,   // bo
    float* __restrict__ Out)        // [4096][1024] f32
{
  const int tid = threadIdx.x, lane = tid & 63, w = tid >> 6;
  const int lin = blockIdx.x + blockIdx.y * 8;
  const int sw  = (lin & 7) * 64 + (lin >> 3);
  const int tile_n = (sw & 7) * 128;
  const int tile_m = (sw >> 3) * 64;
  __shared__ __align__(16) bf16 As[64 * 64];    // 8 KB
  __shared__ __align__(16) bf16 Bs[128 * 64];   // 16 KB

  f32x4 acc[4][2];
#pragma unroll
  for (int i = 0; i < 4; i++)
#pragma unroll
    for (int j = 0; j < 2; j++) acc[i][j] = f32x4{0.f, 0.f, 0.f, 0.f};

  const int quad = lane >> 4, l15 = lane & 15;
  const int srow8 = lane >> 3, p8 = lane & 7;
  const int csrc = p8 ^ srow8;

  for (int k0 = 0; k0 < EMB; k0 += 64) {
#pragma unroll
    for (int i = 0; i < 2; i++) {
      const int ii = w * 2 + i;            // 0..7
      const int r  = ii * 8 + srow8;       // A row 0..63
      gl_lds16(X + (size_t)(tile_m + r) * EMB + k0 + csrc * 8, As + ii * 512);
    }
#pragma unroll
    for (int i = 0; i < 4; i++) {
      const int ii = w * 4 + i;            // 0..15
      const int r  = ii * 8 + srow8;       // B row 0..127
      gl_lds16(W + (size_t)(tile_n + r) * EMB + k0 + csrc * 8, Bs + ii * 512);
    }
    __syncthreads();

#pragma unroll
    for (int kk = 0; kk < 2; kk++) {
      bf16x8 af[4], bfr[2];
#pragma unroll
      for (int mt = 0; mt < 4; mt++) {
        int ml = mt * 16 + l15;
        af[mt] = *(const bf16x8*)(As + ml * 64 + (((kk * 4 + quad) ^ (ml & 7)) & 7) * 8);
      }
#pragma unroll
      for (int nt = 0; nt < 2; nt++) {
        int nl = w * 32 + nt * 16 + l15;
        bfr[nt] = *(const bf16x8*)(Bs + nl * 64 + (((kk * 4 + quad) ^ (nl & 7)) & 7) * 8);
      }
#pragma unroll
      for (int mt = 0; mt < 4; mt++)
#pragma unroll
        for (int nt = 0; nt < 2; nt++)
          acc[mt][nt] = mfma16(af[mt], bfr[nt], acc[mt][nt]);
    }
    __syncthreads();
  }

#pragma unroll
  for (int nt = 0; nt < 2; nt++) {
    const int n = tile_n + w * 32 + nt * 16 + l15;
    const float bias = Bb[n];
#pragma unroll
    for (int mt = 0; mt < 4; mt++) {
#pragma unroll
      for (int r = 0; r < 4; r++) {
        const int m = tile_m + mt * 16 + quad * 4 + r;
        Out[(size_t)m * EMB + n] = acc[mt][nt][r] + bias;
      }
    }
  }
}

// Flash attention v11: occupancy-first restructure.
//  - Block = 64 q rows, grid 1024 (32 bh x 32 qt), LDS = 32 KB (K dbuf ONLY)
//    -> 4 blocks/CU, ~16 waves/CU (2x v10's 8).
//  - k-split across wave pairs: wave (wq = w&1, wk2 = w>>1) computes 32 q x
//    the 64-k half wk2 of each 128-k tile. Swapped-QK keeps P lane-local.
//  - V is NEVER staged: pre-permuted V^T fragments load straight from
//    global/L2 as single b128 per (tl,dt) (addressing validated in v8).
//    Issued BEFORE the kt+1 K-staging so PV's vmcnt wait doesn't drain the
//    prefetch queue. XCD swizzle keeps the 4 heads' K/V in one XCD's L2.
//  - Per wave per kt: 8 LDS b128 (4x fewer), 32 exp2 (2x fewer), 32 MFMA.
//  - Partial O (f32) + lsum combined across the wave pair through LDS after
//    the loop (1 extra barrier); Ks region reused as the combine buffer.
__global__ __launch_bounds__(256) void flash_kernel(
    const bf16* __restrict__ Q,   // [bh][s][d], pre-scaled by log2(e)/8
    const bf16* __restrict__ Kk,  // [bh][s][d]
    const bf16* __restrict__ Vt,  // [bh][d][s], 32-s blocks permuted
    bf16* __restrict__ O)         // [b*S + s][h*64 + d]
{
  const int lin = blockIdx.x + blockIdx.y * 32;   // grid (32,32)
  const int sw  = (lin & 7) * 128 + (lin >> 3);   // 8 XCDs x 128-block chunks
  const int bh  = sw >> 5;                        // 4 heads per XCD chunk
  const int qt  = sw & 31;                        // 64-row q tile
  const int tid = threadIdx.x, lane = tid & 63, w = tid >> 6;
  const int quad = lane >> 4, l15 = lane & 15;
  const int wq = w & 1, wk2 = w >> 1;

  __shared__ __align__(16) unsigned char smem[32768];
  // Ks dbuf: 2 x [128 krow][64 d] bf16, chunk8^(row&7).  After the loop the
  // region is reused: osum float[2][32][68] @0 (17408 B), lsd @17408 (256 B).

  const bf16* qbase = Q  + (size_t)bh * SEQ * HD;
  const bf16* kbase = Kk + (size_t)bh * SEQ * HD;
  const bf16* vbase = Vt + (size_t)bh * HD * SEQ;

  auto stage = [&](int kt, int buf) {
    bf16* Ks = (bf16*)(smem + buf * 16384);
#pragma unroll
    for (int i = 0; i < 4; i++) {
      int r = w * 32 + i * 8 + (lane >> 3);             // K row 0..127
      int c = (lane & 7) ^ (r & 7);
      gl_lds16(kbase + (size_t)(kt * 128 + r) * HD + c * 8, Ks + (w * 32 + i * 8) * 64);
    }
  };

  stage(0, 0);

  // Q fragments: 32 rows (2 m-tiles), B-frag col = l15, k-slots = quad*8+j
  bf16x8 qf[2][2];
#pragma unroll
  for (int m = 0; m < 2; m++)
#pragma unroll
    for (int t = 0; t < 2; t++)
      qf[m][t] = *(const bf16x8*)(qbase + (size_t)(qt * 64 + wq * 32 + m * 16 + l15) * HD
                                  + t * 32 + quad * 8);

  // kt-invariant V element-offsets (per dt); +kt*128 each tile, +tl*32 imm
  int voff[4];
#pragma unroll
  for (int dt = 0; dt < 4; dt++)
    voff[dt] = (dt * 16 + l15) * SEQ + wk2 * 64 + quad * 8;

  float lsum[2] = {0.f, 0.f};
  f32x4 oacc[2][4];
#pragma unroll
  for (int m = 0; m < 2; m++)
#pragma unroll
    for (int i = 0; i < 4; i++) oacc[m][i] = f32x4{0.f, 0.f, 0.f, 0.f};

  __syncthreads();

  for (int kt = 0; kt < SEQ / 128; kt++) {
    const int buf = kt & 1;
    const bf16* Ks = (const bf16*)(smem + buf * 16384);
    const bf16* vkt = vbase + kt * 128;

    // V fragments (global, L2-resident). Slot j of the b128 at
    // vkt + voff[dt] + tl*32 holds k = (wk2*2+tl)*32 + (j>>2)*16 + quad*4
    // + (j&3) — the same permutation as pa. Issue FIRST (before staging).
    bf16x8 vv[2][4];
#pragma unroll
    for (int tl = 0; tl < 2; tl++)
#pragma unroll
      for (int dt = 0; dt < 4; dt++)
        vv[tl][dt] = *(const bf16x8*)(vkt + voff[dt] + tl * 32);

    if (kt + 1 < SEQ / 128) stage(kt + 1, buf ^ 1);   // prefetch next K tile

    __builtin_amdgcn_s_setprio(1);
#pragma unroll
    for (int tl = 0; tl < 2; tl++) {
      // S^T for this wave's k-group: lane holds P[k][q=l15]
      bf16x8 pa[2];
#pragma unroll
      for (int hh = 0; hh < 2; hh++) {
        const int krow = wk2 * 64 + (tl * 2 + hh) * 16 + l15;  // A-frag row=l15
        const int swz = krow & 7;
        bf16x8 kf0 = *(const bf16x8*)(Ks + krow * 64 + ((quad ^ swz) & 7) * 8);
        bf16x8 kf1 = *(const bf16x8*)(Ks + krow * 64 + (((4 + quad) ^ swz) & 7) * 8);
#pragma unroll
        for (int mq = 0; mq < 2; mq++) {
          f32x4 s = f32x4{0.f, 0.f, 0.f, 0.f};
          s = mfma16(kf0, qf[mq][0], s);
          s = mfma16(kf1, qf[mq][1], s);
#pragma unroll
          for (int r = 0; r < 4; r++) {
            float p = __builtin_amdgcn_exp2f(s[r]);
            lsum[mq] += p;
            pa[mq][hh * 4 + r] = (bf16)p;              // slot j=hh*4+r
          }
        }
      }
#pragma unroll
      for (int dt = 0; dt < 4; dt++)
#pragma unroll
        for (int mq = 0; mq < 2; mq++)
          oacc[mq][dt] = mfma16(vv[tl][dt], pa[mq], oacc[mq][dt]);
    }
    __builtin_amdgcn_s_setprio(0);
    __syncthreads();   // K(kt+1) staged + buf free to overwrite
  }

  // ---- wave-pair combine ----
  // quad-reduce: lane -> sum over this wave's 64 k for q = l15
  float ls[2];
#pragma unroll
  for (int mq = 0; mq < 2; mq++) {
    float s = lsum[mq];
    s += __shfl_xor(s, 16, 64);
    s += __shfl_xor(s, 32, 64);
    ls[mq] = s;
  }

  float* osum = (float*)smem;                 // [wq][32 q][68] f32
  float* lsd  = (float*)(smem + 17408);       // [wq][mq][16] f32

  if (wk2 == 1) {
#pragma unroll
    for (int mq = 0; mq < 2; mq++) {
#pragma unroll
      for (int dt = 0; dt < 4; dt++)
        *(f32x4*)&osum[(wq * 32 + mq * 16 + l15) * 68 + dt * 16 + quad * 4] =
            oacc[mq][dt];
      if (quad == 0) lsd[(wq * 2 + mq) * 16 + l15] = ls[mq];
    }
  }
  __syncthreads();

  if (wk2 == 0) {
    const int b = bh >> 4, h = bh & 15;
#pragma unroll
    for (int mq = 0; mq < 2; mq++) {
      const float rls = __builtin_amdgcn_rcpf(ls[mq] + lsd[(wq * 2 + mq) * 16 + l15]);
      const int srow = qt * 64 + wq * 32 + mq * 16 + l15;
      bf16* orow = O + ((size_t)(b * SEQ + srow)) * EMB + h * HD;
#pragma unroll
      for (int dt = 0; dt < 4; dt++) {
        f32x4 a = oacc[mq][dt]
                + *(const f32x4*)&osum[(wq * 32 + mq * 16 + l15) * 68 + dt * 16 + quad * 4];
        bf16x4 ov;
#pragma unroll
        for (int r = 0; r < 4; r++) ov[r] = (bf16)(a[r] * rls);
        *(bf16x4*)(orow + dt * 16 + quad * 4) = ov;    // packed 8B store
      }
    }
  }
}

extern "C" void kernel_launch(void* const* d_in, const int* in_sizes, int n_in,
                              void* d_out, int out_size, void* d_ws, size_t ws_size,
                              hipStream_t stream) {
  const float* x  = (const float*)d_in[0];
  const float* Wq = (const float*)d_in[1];
  const float* bq = (const float*)d_in[2];
  const float* Wk = (const float*)d_in[3];
  const float* bk = (const float*)d_in[4];
  const float* Wv = (const float*)d_in[5];
  const float* bv = (const float*)d_in[6];
  const float* Wo = (const float*)d_in[7];
  const float* bo = (const float*)d_in[8];

  const size_t XN = (size_t)MTOT * EMB;  // 4,194,304
  const size_t WN = (size_t)EMB * EMB;   // 1,048,576

  bf16* xb = (bf16*)d_ws;                // [xb | wq | wk | wv | wo] contiguous
  bf16* wq = xb + XN;
  bf16* wk = wq + WN;
  bf16* wv = wk + WN;
  bf16* wo = wv + WN;
  bf16* q  = wo + WN;
  bf16* k  = q + XN;
  bf16* vt = k + XN;
  bf16* at = vt + XN;
  float* out = (float*)d_out;

  dim3 blk(256);
  cvt_all_kernel<<<dim3(512, 8), blk, 0, stream>>>(x, Wq, Wk, Wv, Wo, xb);

  gemm_kernel<<<dim3(8, 32, 3), blk, 0, stream>>>(
      xb, wq, wk, wv, bq, bk, bv, q, k, vt);
  flash_kernel<<<dim3(32, 32), blk, 0, stream>>>(q, k, vt, at);
  gemm_o_kernel<<<dim3(8, 64), blk, 0, stream>>>(at, wo, bo, out);
}

// Round 7
// 189.731 us; speedup vs baseline: 1.1581x; 1.1581x over previous
//
#include <hip/hip_runtime.h>
#include <hip/hip_bf16.h>
#include <math.h>

typedef __bf16 bf16;
typedef __bf16 bf16x4 __attribute__((ext_vector_type(4)));
typedef __bf16 bf16x8 __attribute__((ext_vector_type(8)));
typedef float f32x4 __attribute__((ext_vector_type(4)));

#define SEQ  2048
#define EMB  1024
#define NH   16
#define HD   64
#define MTOT 4096  // B*S

__device__ __forceinline__ void gl_lds16(const void* g, void* l) {
  __builtin_amdgcn_global_load_lds(
      (const __attribute__((address_space(1))) void*)g,
      (__attribute__((address_space(3))) void*)l, 16, 0, 0);
}

__device__ __forceinline__ f32x4 mfma16(bf16x8 a, bf16x8 b, f32x4 c) {
  return __builtin_amdgcn_mfma_f32_16x16x32_bf16(a, b, c, 0, 0, 0);
}

// log2(10000)/32
#define ROPE_C 0.41524101186092026f
// log2(e)/8 — QK scale, pre-folded into q at the projection epilogue
#define QSCL  0.1803368801111244f

// f32 -> bf16: 8 uniform WN-sized slices; y 0..3 = x chunks, y 4..7 = Wq..Wo.
__global__ __launch_bounds__(256) void cvt_all_kernel(
    const float* __restrict__ x,
    const float* __restrict__ w0, const float* __restrict__ w1,
    const float* __restrict__ w2, const float* __restrict__ w3,
    bf16* __restrict__ dst) {
  const int y = blockIdx.y;
  const size_t WN = (size_t)EMB * EMB;
  const float* src = (y < 4) ? (x + (size_t)y * WN)
                   : (y == 4) ? w0 : (y == 5) ? w1 : (y == 6) ? w2 : w3;
  size_t i = ((size_t)blockIdx.x * 256 + threadIdx.x) * 8;
  float4 a = *(const float4*)(src + i);
  float4 b = *(const float4*)(src + i + 4);
  bf16x8 o;
  o[0] = (bf16)a.x; o[1] = (bf16)a.y; o[2] = (bf16)a.z; o[3] = (bf16)a.w;
  o[4] = (bf16)b.x; o[5] = (bf16)b.y; o[6] = (bf16)b.z; o[7] = (bf16)b.w;
  *(bf16x8*)(dst + (size_t)y * WN + i) = o;
}

// QKV projection (unfused z, 128x128 tile, BK=64): z = blockIdx.z selects
// {q,k,v}. BK=64 halves the barrier/vmcnt(0)-drain count vs BK=32 (the m97
// structural stall) at UNCHANGED occupancy. Swizzle (both-sides, rule 21):
// LDS slot p of row r holds chunk p^(r&7); read uses chunk (kk*4+quad)^(ml&7).
// RoPE on q,k (q pre-scaled by QSCL); q,k -> [bh][s][d], v -> [bh][d][s]
// with each 32-s block PERMUTED for flash's single-b128 PV fragment.
__global__ __launch_bounds__(256) void gemm_kernel(
    const bf16* __restrict__ X,
    const bf16* __restrict__ W0, const bf16* __restrict__ W1, const bf16* __restrict__ W2,
    const float* __restrict__ B0, const float* __restrict__ B1, const float* __restrict__ B2,
    bf16* __restrict__ Oq, bf16* __restrict__ Ok, bf16* __restrict__ Ovt)
{
  const int K = EMB;
  const int tid  = threadIdx.x;
  const int lane = tid & 63;
  const int w    = tid >> 6;       // wave 0..3
  const int wm   = w >> 1, wn = w & 1;
  // XCD swizzle within each z-slice: 32-block chunks per XCD.
  const int lin = blockIdx.x + blockIdx.y * 8;
  const int sw  = (lin & 7) * 32 + (lin >> 3);
  const int tile_n = (sw & 7) * 128;
  const int tile_m = (sw >> 3) * 128;
  const int z = blockIdx.z;
  const bf16*  Wsel = (z == 0) ? W0 : (z == 1 ? W1 : W2);
  const float* Bsel = (z == 0) ? B0 : (z == 1 ? B1 : B2);

  __shared__ __align__(16) unsigned char smem[33792];  // staging 32KB | CS 33792
  bf16* As = (bf16*)smem;            // 128 x 64 = 16 KB
  bf16* Bs = (bf16*)(smem + 16384);  // 128 x 64 = 16 KB

  f32x4 acc[4][4];
#pragma unroll
  for (int i = 0; i < 4; i++)
#pragma unroll
    for (int j = 0; j < 4; j++) acc[i][j] = f32x4{0.f, 0.f, 0.f, 0.f};

  const int quad  = lane >> 4;
  const int l15   = lane & 15;
  const int srow8 = lane >> 3;   // row within an 8-row staging issue
  const int p8    = lane & 7;    // 16B-chunk slot within the 128B row
  const int csrc  = p8 ^ srow8;  // global chunk feeding this LDS slot

  for (int k0 = 0; k0 < K; k0 += 64) {
#pragma unroll
    for (int i = 0; i < 4; i++) {
      const int ii = w * 4 + i;            // 8-row group 0..15
      const int r  = ii * 8 + srow8;       // tile-local row 0..127
      gl_lds16(X    + (size_t)(tile_m + r) * K + k0 + csrc * 8, As + ii * 512);
      gl_lds16(Wsel + (size_t)(tile_n + r) * K + k0 + csrc * 8, Bs + ii * 512);
    }
    __syncthreads();

#pragma unroll
    for (int kk = 0; kk < 2; kk++) {
      bf16x8 af[4], bfr[4];
#pragma unroll
      for (int mt = 0; mt < 4; mt++) {
        int ml = wm * 64 + mt * 16 + l15;
        af[mt] = *(const bf16x8*)(As + ml * 64 + (((kk * 4 + quad) ^ (ml & 7)) & 7) * 8);
      }
#pragma unroll
      for (int nt = 0; nt < 4; nt++) {
        int nl = wn * 64 + nt * 16 + l15;
        bfr[nt] = *(const bf16x8*)(Bs + nl * 64 + (((kk * 4 + quad) ^ (nl & 7)) & 7) * 8);
      }
#pragma unroll
      for (int mt = 0; mt < 4; mt++)
#pragma unroll
        for (int nt = 0; nt < 4; nt++)
          acc[mt][nt] = mfma16(af[mt], bfr[nt], acc[mt][nt]);
    }
    __syncthreads();
  }

  // ---- epilogue ----
  bf16* CS = (bf16*)smem;  // 128 rows x 132 stride
  const int b = tile_m >> 11;
  const int s0 = tile_m & (SEQ - 1);

  if (z < 2) {
    // bias + RoPE in registers, stage CS[m][n]
#pragma unroll
    for (int nt = 0; nt < 4; nt++) {
      const int nl = wn * 64 + nt * 16 + l15;
      const int n = tile_n + nl;
      const float bias = Bsel[n];
      const int j = n & 31;
      const float invf = exp2f(-(float)j * ROPE_C);
#pragma unroll
      for (int mt = 0; mt < 4; mt++) {
#pragma unroll
        for (int r = 0; r < 4; r++) {
          const int ml = wm * 64 + mt * 16 + quad * 4 + r;
          float a = acc[mt][nt][r] + bias;
          float p = __shfl_xor(a, 1, 64);  // partner at d^1 (incl. its bias)
          float th = (float)(s0 + ml) * invf;
          float sn, cs;
          __sincosf(th, &sn, &cs);
          float res = (n & 1) ? fmaf(p, sn, a * cs) : fmaf(-p, sn, a * cs);
          if (z == 0) res *= QSCL;  // fold QK scale+log2e into q
          CS[ml * 132 + nl] = (bf16)res;
        }
      }
    }
    __syncthreads();
    // coalesced store: 256 rows (2 heads x 128 s), 128 B each
    bf16* Odst = (z == 0) ? Oq : Ok;
#pragma unroll
    for (int g = 0; g < 8; g++) {
      int unit = g * 256 + tid;
      int chunk = unit & 7;          // 16B chunk within row
      int row = unit >> 3;           // 0..255
      int hl = row >> 7, sl = row & 127;
      bf16x8 v = *(const bf16x8*)(CS + sl * 132 + hl * 64 + chunk * 8);
      int hg = (tile_n >> 6) + hl;
      size_t o = ((size_t)(b * NH + hg) * SEQ + s0 + sl) * HD + chunk * 8;
      *(bf16x8*)(Odst + o) = v;
    }
  } else {
    // V^T: stage CS[n][perm(m)] — permute s within each 32-block so flash's
    // per-lane fragment (k = hf*16 + quad*4 + e -> pos quad*8 + hf*4 + e) is
    // contiguous 16B.
#pragma unroll
    for (int nt = 0; nt < 4; nt++) {
      const int nl = wn * 64 + nt * 16 + l15;
      const float bias = Bsel[tile_n + nl];
#pragma unroll
      for (int mt = 0; mt < 4; mt++) {
        const int mb = wm * 64 + mt * 16 + quad * 4;
#pragma unroll
        for (int r = 0; r < 4; r++) {
          const int ml = mb + r;
          const int mp = (ml & ~31) | ((ml & 12) << 1) | ((ml & 16) >> 2) | (ml & 3);
          CS[nl * 132 + mp] = (bf16)(acc[mt][nt][r] + bias);
        }
      }
    }
    __syncthreads();
    // coalesced store: 128 rows (d), 256 B each
#pragma unroll
    for (int g = 0; g < 8; g++) {
      int unit = g * 256 + tid;
      int chunk = unit & 15;         // 16B chunk within row
      int row = unit >> 4;           // 0..127 (n_local)
      bf16x8 v = *(const bf16x8*)(CS + row * 132 + chunk * 8);
      int nglob = tile_n + row;
      int d = nglob & 63, hg = nglob >> 6;
      size_t o = ((size_t)(b * NH + hg) * HD + d) * SEQ + s0 + chunk * 8;
      *(bf16x8*)(Ovt + o) = v;
    }
  }
}

// Out projection: 64x128 tiles, BK=64, 512 blocks. XCD-swizzled.
__global__ __launch_bounds__(256) void gemm_o_kernel(
    const bf16* __restrict__ X,     // attn out [4096][1024] bf16
    const bf16* __restrict__ W,     // Wo [1024][1024] bf16
    const float* __restrict__ Bb,   // bo
    float* __restrict__ Out)        // [4096][1024] f32
{
  const int tid = threadIdx.x, lane = tid & 63, w = tid >> 6;
  const int lin = blockIdx.x + blockIdx.y * 8;
  const int sw  = (lin & 7) * 64 + (lin >> 3);
  const int tile_n = (sw & 7) * 128;
  const int tile_m = (sw >> 3) * 64;
  __shared__ __align__(16) bf16 As[64 * 64];    // 8 KB
  __shared__ __align__(16) bf16 Bs[128 * 64];   // 16 KB

  f32x4 acc[4][2];
#pragma unroll
  for (int i = 0; i < 4; i++)
#pragma unroll
    for (int j = 0; j < 2; j++) acc[i][j] = f32x4{0.f, 0.f, 0.f, 0.f};

  const int quad = lane >> 4, l15 = lane & 15;
  const int srow8 = lane >> 3, p8 = lane & 7;
  const int csrc = p8 ^ srow8;

  for (int k0 = 0; k0 < EMB; k0 += 64) {
#pragma unroll
    for (int i = 0; i < 2; i++) {
      const int ii = w * 2 + i;            // 0..7
      const int r  = ii * 8 + srow8;       // A row 0..63
      gl_lds16(X + (size_t)(tile_m + r) * EMB + k0 + csrc * 8, As + ii * 512);
    }
#pragma unroll
    for (int i = 0; i < 4; i++) {
      const int ii = w * 4 + i;            // 0..15
      const int r  = ii * 8 + srow8;       // B row 0..127
      gl_lds16(W + (size_t)(tile_n + r) * EMB + k0 + csrc * 8, Bs + ii * 512);
    }
    __syncthreads();

#pragma unroll
    for (int kk = 0; kk < 2; kk++) {
      bf16x8 af[4], bfr[2];
#pragma unroll
      for (int mt = 0; mt < 4; mt++) {
        int ml = mt * 16 + l15;
        af[mt] = *(const bf16x8*)(As + ml * 64 + (((kk * 4 + quad) ^ (ml & 7)) & 7) * 8);
      }
#pragma unroll
      for (int nt = 0; nt < 2; nt++) {
        int nl = w * 32 + nt * 16 + l15;
        bfr[nt] = *(const bf16x8*)(Bs + nl * 64 + (((kk * 4 + quad) ^ (nl & 7)) & 7) * 8);
      }
#pragma unroll
      for (int mt = 0; mt < 4; mt++)
#pragma unroll
        for (int nt = 0; nt < 2; nt++)
          acc[mt][nt] = mfma16(af[mt], bfr[nt], acc[mt][nt]);
    }
    __syncthreads();
  }

#pragma unroll
  for (int nt = 0; nt < 2; nt++) {
    const int n = tile_n + w * 32 + nt * 16 + l15;
    const float bias = Bb[n];
#pragma unroll
    for (int mt = 0; mt < 4; mt++) {
#pragma unroll
      for (int r = 0; r < 4; r++) {
        const int m = tile_m + mt * 16 + quad * 4 + r;
        Out[(size_t)m * EMB + n] = acc[mt][nt][r] + bias;
      }
    }
  }
}

// Flash attention v12 = v10 (R5-verified, 50.4 µs) + ones-MFMA row-sum:
// lsum's 64 serial VALU adds/kt (dependent on each exp2) move to the MFMA
// pipe as mfma16(ones, pa) — 8 extra MFMA/kt on a 27%-utilized pipe, and the
// denominator now uses the SAME bf16-rounded P as the PV numerator (ratio
// consistency improves). End-of-loop shuffles also disappear (every output
// row of the ones-MFMA holds the full k-sum for q = l15).
__global__ __launch_bounds__(256) void flash_kernel(
    const bf16* __restrict__ Q,   // [bh][s][d], pre-scaled by log2(e)/8
    const bf16* __restrict__ Kk,  // [bh][s][d]
    const bf16* __restrict__ Vt,  // [bh][d][s], 32-s blocks permuted
    bf16* __restrict__ O)         // [b*S + s][h*64 + d]
{
  const int lin = blockIdx.x + blockIdx.y * 16;   // dispatch-linear, x fastest
  const int sw  = (lin & 7) * 64 + (lin >> 3);    // 8 XCDs x 64-block chunks
  const int bh  = sw >> 4;                        // 4 heads per XCD chunk
  const int qt  = sw & 15;                        // 128-row q tile
  const int tid = threadIdx.x, lane = tid & 63, w = tid >> 6;
  const int quad = lane >> 4, l15 = lane & 15;

  __shared__ __align__(16) unsigned char smem[65536];
  // buf b at smem + b*32768: [Ks 16KB: 128 krow x 64 d, chunk8^(row&7)]
  //                          [Vs 16KB:  64 d x 128 s,  chunk16^(d&15)]

  const bf16* qbase = Q  + (size_t)bh * SEQ * HD;
  const bf16* kbase = Kk + (size_t)bh * SEQ * HD;
  const bf16* vbase = Vt + (size_t)bh * HD * SEQ;

  // stage one K/V tile into buffer `buf` (zero-conflict pattern)
  auto stage = [&](int kt, int buf) {
    bf16* Ks = (bf16*)(smem + buf * 32768);
    bf16* Vs = Ks + 8192;
#pragma unroll
    for (int i = 0; i < 4; i++) {
      int r = w * 32 + i * 8 + (lane >> 3);             // K row 0..127
      int c = (lane & 7) ^ (r & 7);
      gl_lds16(kbase + (size_t)(kt * 128 + r) * HD + c * 8, Ks + (w * 32 + i * 8) * 64);
      int dv = w * 16 + i * 4 + (lane >> 4);            // V^T row (d) 0..63
      int cv = (lane & 15) ^ (dv & 15);
      gl_lds16(vbase + (size_t)dv * SEQ + kt * 128 + cv * 8, Vs + (w * 16 + i * 4) * 128);
    }
  };

  stage(0, 0);

  // preload this wave's 32 q rows (B-frag layout: col = l15, k = quad*8+j)
  bf16x8 qf[2][2];
#pragma unroll
  for (int m = 0; m < 2; m++)
#pragma unroll
    for (int t = 0; t < 2; t++)
      qf[m][t] = *(const bf16x8*)(qbase + (size_t)(qt * 128 + w * 32 + m * 16 + l15) * HD
                                  + t * 32 + quad * 8);

  // all-ones A-fragment for the row-sum MFMA
  bf16x8 ones;
#pragma unroll
  for (int i = 0; i < 8; i++) ones[i] = (bf16)1.0f;

  f32x4 lacc[2];
  f32x4 oacc[2][4];
#pragma unroll
  for (int m = 0; m < 2; m++) {
    lacc[m] = f32x4{0.f, 0.f, 0.f, 0.f};
#pragma unroll
    for (int i = 0; i < 4; i++) oacc[m][i] = f32x4{0.f, 0.f, 0.f, 0.f};
  }

  __syncthreads();

  for (int kt = 0; kt < SEQ / 128; kt++) {
    const int buf = kt & 1;
    if (kt + 1 < SEQ / 128) stage(kt + 1, buf ^ 1);   // prefetch next tile
    const bf16* Ks = (const bf16*)(smem + buf * 32768);
    const bf16* Vs = Ks + 8192;

    __builtin_amdgcn_s_setprio(1);
#pragma unroll
    for (int t2 = 0; t2 < 4; t2++) {
      // S^T for k-block t2*32..t2*32+31: lane holds P[k=mk*16+quad*4+r][q=l15]
      bf16x8 pa[2];
#pragma unroll
      for (int hh = 0; hh < 2; hh++) {
        const int krow = (t2 * 2 + hh) * 16 + l15;     // A-frag: row = l15
        const int swz = krow & 7;
        bf16x8 kf0 = *(const bf16x8*)(Ks + krow * 64 + ((quad ^ swz) & 7) * 8);
        bf16x8 kf1 = *(const bf16x8*)(Ks + krow * 64 + (((4 + quad) ^ swz) & 7) * 8);
#pragma unroll
        for (int mq = 0; mq < 2; mq++) {
          f32x4 s = f32x4{0.f, 0.f, 0.f, 0.f};
          s = mfma16(kf0, qf[mq][0], s);
          s = mfma16(kf1, qf[mq][1], s);
#pragma unroll
          for (int r = 0; r < 4; r++)
            pa[mq][hh * 4 + r] = (bf16)__builtin_amdgcn_exp2f(s[r]);
        }
      }
      // PV: V pre-permuted so the b128 at chunk (t2*4+quad)^l15 holds exactly
      // k = t2*32 + (j>>2)*16 + quad*4 + (j&3) at slot j — matching pa.
#pragma unroll
      for (int dt = 0; dt < 4; dt++) {
        const int d = dt * 16 + l15;
        bf16x8 vv = *(const bf16x8*)(Vs + d * 128 + ((t2 * 4 + quad) ^ l15) * 8);
#pragma unroll
        for (int mq = 0; mq < 2; mq++)
          oacc[mq][dt] = mfma16(vv, pa[mq], oacc[mq][dt]);
      }
      // row-sum on the MFMA pipe: every output row = sum_k pa[k][q=l15]
#pragma unroll
      for (int mq = 0; mq < 2; mq++)
        lacc[mq] = mfma16(ones, pa[mq], lacc[mq]);
    }
    __builtin_amdgcn_s_setprio(0);
    __syncthreads();   // one barrier/kt: prefetch landed + buf free to overwrite
  }

  // rls straight from lacc (all 4 rows identical; no cross-lane reduce needed)
  float rls[2];
#pragma unroll
  for (int mq = 0; mq < 2; mq++)
    rls[mq] = __builtin_amdgcn_rcpf(lacc[mq][0]);

  // O^T blocks: oacc[mq][dt][r] = O[q = mq*16+l15][d = dt*16+quad*4+r]
  const int b = bh >> 4, h = bh & 15;
#pragma unroll
  for (int mq = 0; mq < 2; mq++) {
    const int srow = qt * 128 + w * 32 + mq * 16 + l15;
    bf16* orow = O + ((size_t)(b * SEQ + srow)) * EMB + h * HD;
#pragma unroll
    for (int dt = 0; dt < 4; dt++) {
      bf16x4 ov;
#pragma unroll
      for (int r = 0; r < 4; r++) ov[r] = (bf16)(oacc[mq][dt][r] * rls[mq]);
      *(bf16x4*)(orow + dt * 16 + quad * 4) = ov;      // packed 8B store
    }
  }
}

extern "C" void kernel_launch(void* const* d_in, const int* in_sizes, int n_in,
                              void* d_out, int out_size, void* d_ws, size_t ws_size,
                              hipStream_t stream) {
  const float* x  = (const float*)d_in[0];
  const float* Wq = (const float*)d_in[1];
  const float* bq = (const float*)d_in[2];
  const float* Wk = (const float*)d_in[3];
  const float* bk = (const float*)d_in[4];
  const float* Wv = (const float*)d_in[5];
  const float* bv = (const float*)d_in[6];
  const float* Wo = (const float*)d_in[7];
  const float* bo = (const float*)d_in[8];

  const size_t XN = (size_t)MTOT * EMB;  // 4,194,304
  const size_t WN = (size_t)EMB * EMB;   // 1,048,576

  bf16* xb = (bf16*)d_ws;                // [xb | wq | wk | wv | wo] contiguous
  bf16* wq = xb + XN;
  bf16* wk = wq + WN;
  bf16* wv = wk + WN;
  bf16* wo = wv + WN;
  bf16* q  = wo + WN;
  bf16* k  = q + XN;
  bf16* vt = k + XN;
  bf16* at = vt + XN;
  float* out = (float*)d_out;

  dim3 blk(256);
  cvt_all_kernel<<<dim3(512, 8), blk, 0, stream>>>(x, Wq, Wk, Wv, Wo, xb);

  gemm_kernel<<<dim3(8, 32, 3), blk, 0, stream>>>(
      xb, wq, wk, wv, bq, bk, bv, q, k, vt);
  flash_kernel<<<dim3(16, 32), blk, 0, stream>>>(q, k, vt, at);
  gemm_o_kernel<<<dim3(8, 64), blk, 0, stream>>>(at, wo, bo, out);
}